// Round 4
// baseline (1092.024 us; speedup 1.0000x reference)
//
#include <hip/hip_runtime.h>

typedef float4 f4;
typedef float nf4 __attribute__((ext_vector_type(4)));   // native vector for nontemporal builtins

__device__ __forceinline__ f4 ld4(const float* p) { return *reinterpret_cast<const f4*>(p); }

__device__ __forceinline__ nf4 ldnt4(const float* p) {
    return __builtin_nontemporal_load(reinterpret_cast<const nf4*>(p));
}
__device__ __forceinline__ void stnt4(float* p, nf4 v) {
    __builtin_nontemporal_store(v, reinterpret_cast<nf4*>(p));
}
__device__ __forceinline__ void stnt4f(float* p, f4 v) {
    nf4 t; t.x = v.x; t.y = v.y; t.z = v.z; t.w = v.w;
    __builtin_nontemporal_store(t, reinterpret_cast<nf4*>(p));
}

__device__ __forceinline__ f4 fma4(float w, f4 a, f4 c) {
    c.x = fmaf(w, a.x, c.x); c.y = fmaf(w, a.y, c.y);
    c.z = fmaf(w, a.z, c.z); c.w = fmaf(w, a.w, c.w);
    return c;
}

// Lane-parallel fake-quant: lanes 0..NW-1 each quantize ONE weight (fp32 divide,
// rint = round-half-even, clip, rescale — bit-exact vs reference), then broadcast
// all NW results to wave-uniform SGPR values via v_readlane.
template<int NW>
__device__ __forceinline__ void quant_bcast(const float* __restrict__ wb, float s, float* wq) {
    int lane = threadIdx.x & 63;
    float q = 0.f;
    if (lane < NW) {
        float r = rintf(wb[lane] / s);
        r = fminf(fmaxf(r, -8.f), 7.f);
        q = r * s;
    }
#pragma unroll
    for (int k = 0; k < NW; k++)
        wq[k] = __int_as_float(__builtin_amdgcn_readlane(__float_as_int(q), k));
}

// Fused kernel, section-blocked grid (20480 blocks total):
//   [0, 4096)      : identity copy, channels 0..63
//   [4096, 8192)   : conv_h  (11x1, pad (5,5),(0,0)), channels 64..127   4 rows x 4 px/thread
//   [8192, 16384)  : conv_w  (1x11, pad (0,0),(5,5)), channels 128..191  1 row x 8 px/thread
//   [16384, 20480) : conv_hw (3x3,  pad (1,1),(1,1)), channels 192..255  2 rows x 8 px/thread
// All sections designed for <=~48 live VGPRs so the launch-bounds clamp (observed
// cap 64 under (256,4)) causes NO spills.
__global__ __launch_bounds__(256, 4) void fused_k(
    const float* __restrict__ x,
    const float* __restrict__ w_h,  const float* __restrict__ b_h,  const float* __restrict__ s_h,
    const float* __restrict__ w_w,  const float* __restrict__ b_w,  const float* __restrict__ s_w,
    const float* __restrict__ w_hw, const float* __restrict__ b_hw, const float* __restrict__ s_hw,
    float* __restrict__ out)
{
    int blk  = blockIdx.x;
    int wave = threadIdx.x >> 6;
    int lane = threadIdx.x & 63;

    if (blk < 4096) {
        // ---------------- identity: streaming copy, nontemporal both ways --------
        int idx = (blk << 8) + threadIdx.x;          // 1,048,576 threads
#pragma unroll
        for (int t = 0; t < 4; t++) {
            int i   = idx + t * 1048576;             // f4 index in id-section space
            int n   = i >> 16;                       // 65536 f4 per n
            int rem = i & 65535;
            size_t off = ((size_t)n * 262144 + rem) * 4;  // float units
            stnt4(out + off, ldnt4(x + off));
        }
        return;
    }

    if (blk < 8192) {
        // ---------------- conv_h: 11x1 vertical ----------------------------------
        int b = blk - 4096;                          // 0..4095 : 64 n * 16 g * 4 strips
        int n = b >> 6, g = (b >> 2) & 15, strip = b & 3;
        int oc = g * 4 + wave;
        float wq[44];
        quant_bcast<44>(w_h + oc * 44, s_h[0], wq);
        float bz = b_h[oc];
        int x0 = (lane & 15) << 2;                   // lanes 0..15 span a full 64-px row
        int y0 = strip * 16 + (lane >> 4) * 4;       // 4 consecutive rows per thread

        f4 acc[4];
#pragma unroll
        for (int r = 0; r < 4; r++) { acc[r].x = bz; acc[r].y = bz; acc[r].z = bz; acc[r].w = bz; }

        const float* xin = x + n * 1048576 + (64 + g * 4) * 4096 + x0;
#pragma unroll
        for (int ic = 0; ic < 4; ic++) {
            const float* pl = xin + ic * 4096;
#pragma unroll
            for (int j = 0; j < 14; j++) {           // input rows y0-5 .. y0+8
                int y  = y0 - 5 + j;
                int yc = min(max(y, 0), 63);         // clamped: always-legal load
                f4 v = ld4(pl + yc * 64);
                if (y != yc) { v.x = 0.f; v.y = 0.f; v.z = 0.f; v.w = 0.f; }
#pragma unroll
                for (int r = 0; r < 4; r++) {
                    int k = j - r;
                    if (k >= 0 && k < 11)            // compile-time after unroll
                        acc[r] = fma4(wq[ic * 11 + k], v, acc[r]);
                }
            }
        }
        float* po = out + n * 1048576 + (64 + oc) * 4096 + y0 * 64 + x0;
#pragma unroll
        for (int r = 0; r < 4; r++) stnt4f(po + r * 64, acc[r]);
        return;
    }

    if (blk < 16384) {
        // ---------------- conv_w: 1x11 horizontal --------------------------------
        int b = blk - 8192;                          // 0..8191 : 64 n * 16 g * 8 strips
        int n = b >> 7, g = (b >> 3) & 15, strip = b & 7;
        int oc = g * 4 + wave;
        float wq[44];
        quant_bcast<44>(w_w + oc * 44, s_w[0], wq);
        float bz = b_w[oc];
        int row = strip * 8 + (lane >> 3);           // 8 consecutive rows per wave
        int x0  = (lane & 7) << 3;                   // lanes 0..7 span a full row

        float acc[8];
#pragma unroll
        for (int p = 0; p < 8; p++) acc[p] = bz;

        const float* xin = x + n * 1048576 + (128 + g * 4) * 4096 + row * 64;
#pragma unroll
        for (int ic = 0; ic < 4; ic++) {
            const float* pl = xin + ic * 4096;
            float buf[24];                           // px x0-8 .. x0+15
#pragma unroll
            for (int t = 0; t < 6; t++) {
                int xb = x0 - 8 + t * 4;
                int xc = min(max(xb, 0), 60);
                f4 v = ld4(pl + xc);
                if (xb != xc) { v.x = 0.f; v.y = 0.f; v.z = 0.f; v.w = 0.f; }
                buf[t * 4 + 0] = v.x; buf[t * 4 + 1] = v.y;
                buf[t * 4 + 2] = v.z; buf[t * 4 + 3] = v.w;
            }
#pragma unroll
            for (int p = 0; p < 8; p++)
#pragma unroll
                for (int k = 0; k < 11; k++)
                    acc[p] = fmaf(wq[ic * 11 + k], buf[p + k + 3], acc[p]);
        }
        float* po = out + n * 1048576 + (128 + oc) * 4096 + row * 64 + x0;
#pragma unroll
        for (int t = 0; t < 2; t++) {
            f4 v; v.x = acc[t * 4]; v.y = acc[t * 4 + 1]; v.z = acc[t * 4 + 2]; v.w = acc[t * 4 + 3];
            stnt4f(po + t * 4, v);
        }
        return;
    }

    {
        // ---------------- conv_hw: 3x3, streamed input rows ----------------------
        int b = blk - 16384;                         // 0..4095 : 64 n * 16 g * 4 strips
        int n = b >> 6, g = (b >> 2) & 15, strip = b & 3;
        int oc = g * 4 + wave;
        float wq[36];
        quant_bcast<36>(w_hw + oc * 36, s_hw[0], wq);
        float bz = b_hw[oc];
        int yp = strip * 16 + (lane >> 3) * 2;       // 2 rows per thread
        int x0 = (lane & 7) << 3;                    // lanes 0..7 span a full row

        float acc[2][8];
#pragma unroll
        for (int r = 0; r < 2; r++)
#pragma unroll
            for (int p = 0; p < 8; p++) acc[r][p] = bz;

        const float* xin = x + n * 1048576 + (192 + g * 4) * 4096;
#pragma unroll
        for (int ic = 0; ic < 4; ic++) {
            const float* pl = xin + ic * 4096;
#pragma unroll
            for (int iy = 0; iy < 4; iy++) {         // stream rows yp-1 .. yp+2
                int y  = yp - 1 + iy;
                int yc = min(max(y, 0), 63);
                bool yok = (y == yc);
                float rowb[16];                      // px x0-4 .. x0+11
#pragma unroll
                for (int t = 0; t < 4; t++) {
                    int xb = x0 - 4 + t * 4;
                    int xc = min(max(xb, 0), 60);
                    f4 v = ld4(pl + yc * 64 + xc);
                    if (!yok || xb != xc) { v.x = 0.f; v.y = 0.f; v.z = 0.f; v.w = 0.f; }
                    rowb[t * 4 + 0] = v.x; rowb[t * 4 + 1] = v.y;
                    rowb[t * 4 + 2] = v.z; rowb[t * 4 + 3] = v.w;
                }
#pragma unroll
                for (int r = 0; r < 2; r++) {
                    int ky = iy - r;                 // compile-time after unroll
                    if (ky >= 0 && ky < 3) {
#pragma unroll
                        for (int p = 0; p < 8; p++)
#pragma unroll
                            for (int kx = 0; kx < 3; kx++)
                                acc[r][p] = fmaf(wq[(ic * 3 + ky) * 3 + kx],
                                                 rowb[p + kx + 3], acc[r][p]);
                    }
                }
            }
        }
        float* po = out + n * 1048576 + (192 + oc) * 4096 + yp * 64 + x0;
#pragma unroll
        for (int r = 0; r < 2; r++)
#pragma unroll
            for (int t = 0; t < 2; t++) {
                f4 v;
                v.x = acc[r][t * 4]; v.y = acc[r][t * 4 + 1];
                v.z = acc[r][t * 4 + 2]; v.w = acc[r][t * 4 + 3];
                stnt4f(po + r * 64 + t * 4, v);
            }
    }
}

extern "C" void kernel_launch(void* const* d_in, const int* in_sizes, int n_in,
                              void* d_out, int out_size, void* d_ws, size_t ws_size,
                              hipStream_t stream) {
    // setup_inputs order: x, w_hw, b_hw, s_hw, w_w, b_w, s_w, w_h, b_h, s_h
    const float* x    = (const float*)d_in[0];
    const float* w_hw = (const float*)d_in[1];
    const float* b_hw = (const float*)d_in[2];
    const float* s_hw = (const float*)d_in[3];
    const float* w_w  = (const float*)d_in[4];
    const float* b_w  = (const float*)d_in[5];
    const float* s_w  = (const float*)d_in[6];
    const float* w_h  = (const float*)d_in[7];
    const float* b_h  = (const float*)d_in[8];
    const float* s_h  = (const float*)d_in[9];
    float* out = (float*)d_out;

    fused_k<<<20480, 256, 0, stream>>>(x, w_h, b_h, s_h, w_w, b_w, s_w,
                                       w_hw, b_hw, s_hw, out);
}

// Round 5
// 575.600 us; speedup vs baseline: 1.8972x; 1.8972x over previous
//
#include <hip/hip_runtime.h>

typedef float4 f4;
typedef float nf4 __attribute__((ext_vector_type(4)));   // native vector for nontemporal builtins

__device__ __forceinline__ f4 ld4(const float* p) { return *reinterpret_cast<const f4*>(p); }

__device__ __forceinline__ nf4 ldnt4(const float* p) {
    return __builtin_nontemporal_load(reinterpret_cast<const nf4*>(p));
}
__device__ __forceinline__ void stnt4(float* p, nf4 v) {
    __builtin_nontemporal_store(v, reinterpret_cast<nf4*>(p));
}
__device__ __forceinline__ void stnt4f(float* p, f4 v) {
    nf4 t; t.x = v.x; t.y = v.y; t.z = v.z; t.w = v.w;
    __builtin_nontemporal_store(t, reinterpret_cast<nf4*>(p));
}

__device__ __forceinline__ f4 fma4(float w, f4 a, f4 c) {
    c.x = fmaf(w, a.x, c.x); c.y = fmaf(w, a.y, c.y);
    c.z = fmaf(w, a.z, c.z); c.w = fmaf(w, a.w, c.w);
    return c;
}

// Lane-parallel fake-quant: lanes 0..NW-1 each quantize ONE weight (fp32 divide,
// rint = round-half-even, clip, rescale — bit-exact vs reference), then broadcast
// all NW results to wave-uniform SGPR values via v_readlane.
template<int NW>
__device__ __forceinline__ void quant_bcast(const float* __restrict__ wb, float s, float* wq) {
    int lane = threadIdx.x & 63;
    float q = 0.f;
    if (lane < NW) {
        float r = rintf(wb[lane] / s);
        r = fminf(fmaxf(r, -8.f), 7.f);
        q = r * s;
    }
#pragma unroll
    for (int k = 0; k < NW; k++)
        wq[k] = __int_as_float(__builtin_amdgcn_readlane(__float_as_int(q), k));
}

// Fused kernel, section-blocked grid (20480 blocks total):
//   [0, 4096)      : identity copy, channels 0..63
//   [4096, 8192)   : conv_h  (11x1, pad (5,5),(0,0)), channels 64..127   4 rows x 4 px/thread
//   [8192, 16384)  : conv_w  (1x11, pad (0,0),(5,5)), channels 128..191  1 row x 8 px/thread
//   [16384, 20480) : conv_hw (3x3,  pad (1,1),(1,1)), channels 192..255  2 rows x 8 px/thread
// NOTE: no min-waves clamp. Rounds 3/4 proved __launch_bounds__(256,4) forces
// VGPR=64 and turns the conv sections into scratch-spill storms (+2.3 GB HBM).
// Natural allocation for these lean streaming bodies should be ~80-112 VGPR,
// zero spill, 4-6 waves/SIMD.
__global__ __launch_bounds__(256) void fused_k(
    const float* __restrict__ x,
    const float* __restrict__ w_h,  const float* __restrict__ b_h,  const float* __restrict__ s_h,
    const float* __restrict__ w_w,  const float* __restrict__ b_w,  const float* __restrict__ s_w,
    const float* __restrict__ w_hw, const float* __restrict__ b_hw, const float* __restrict__ s_hw,
    float* __restrict__ out)
{
    int blk  = blockIdx.x;
    int wave = threadIdx.x >> 6;
    int lane = threadIdx.x & 63;

    if (blk < 4096) {
        // ---------------- identity: streaming copy, nontemporal both ways --------
        int idx = (blk << 8) + threadIdx.x;          // 1,048,576 threads
#pragma unroll
        for (int t = 0; t < 4; t++) {
            int i   = idx + t * 1048576;             // f4 index in id-section space
            int n   = i >> 16;                       // 65536 f4 per n
            int rem = i & 65535;
            size_t off = ((size_t)n * 262144 + rem) * 4;  // float units
            stnt4(out + off, ldnt4(x + off));
        }
        return;
    }

    if (blk < 8192) {
        // ---------------- conv_h: 11x1 vertical ----------------------------------
        int b = blk - 4096;                          // 0..4095 : 64 n * 16 g * 4 strips
        int n = b >> 6, g = (b >> 2) & 15, strip = b & 3;
        int oc = g * 4 + wave;
        float wq[44];
        quant_bcast<44>(w_h + oc * 44, s_h[0], wq);
        float bz = b_h[oc];
        int x0 = (lane & 15) << 2;                   // lanes 0..15 span a full 64-px row
        int y0 = strip * 16 + (lane >> 4) * 4;       // 4 consecutive rows per thread

        f4 acc[4];
#pragma unroll
        for (int r = 0; r < 4; r++) { acc[r].x = bz; acc[r].y = bz; acc[r].z = bz; acc[r].w = bz; }

        const float* xin = x + n * 1048576 + (64 + g * 4) * 4096 + x0;
#pragma unroll
        for (int ic = 0; ic < 4; ic++) {
            const float* pl = xin + ic * 4096;
#pragma unroll
            for (int j = 0; j < 14; j++) {           // input rows y0-5 .. y0+8
                int y  = y0 - 5 + j;
                int yc = min(max(y, 0), 63);         // clamped: always-legal load
                f4 v = ld4(pl + yc * 64);
                if (y != yc) { v.x = 0.f; v.y = 0.f; v.z = 0.f; v.w = 0.f; }
#pragma unroll
                for (int r = 0; r < 4; r++) {
                    int k = j - r;
                    if (k >= 0 && k < 11)            // compile-time after unroll
                        acc[r] = fma4(wq[ic * 11 + k], v, acc[r]);
                }
            }
        }
        float* po = out + n * 1048576 + (64 + oc) * 4096 + y0 * 64 + x0;
#pragma unroll
        for (int r = 0; r < 4; r++) stnt4f(po + r * 64, acc[r]);
        return;
    }

    if (blk < 16384) {
        // ---------------- conv_w: 1x11 horizontal --------------------------------
        int b = blk - 8192;                          // 0..8191 : 64 n * 16 g * 8 strips
        int n = b >> 7, g = (b >> 3) & 15, strip = b & 7;
        int oc = g * 4 + wave;
        float wq[44];
        quant_bcast<44>(w_w + oc * 44, s_w[0], wq);
        float bz = b_w[oc];
        int row = strip * 8 + (lane >> 3);           // 8 consecutive rows per wave
        int x0  = (lane & 7) << 3;                   // lanes 0..7 span a full row

        float acc[8];
#pragma unroll
        for (int p = 0; p < 8; p++) acc[p] = bz;

        const float* xin = x + n * 1048576 + (128 + g * 4) * 4096 + row * 64;
#pragma unroll
        for (int ic = 0; ic < 4; ic++) {
            const float* pl = xin + ic * 4096;
            float buf[24];                           // px x0-8 .. x0+15
#pragma unroll
            for (int t = 0; t < 6; t++) {
                int xb = x0 - 8 + t * 4;
                int xc = min(max(xb, 0), 60);
                f4 v = ld4(pl + xc);
                if (xb != xc) { v.x = 0.f; v.y = 0.f; v.z = 0.f; v.w = 0.f; }
                buf[t * 4 + 0] = v.x; buf[t * 4 + 1] = v.y;
                buf[t * 4 + 2] = v.z; buf[t * 4 + 3] = v.w;
            }
#pragma unroll
            for (int p = 0; p < 8; p++)
#pragma unroll
                for (int k = 0; k < 11; k++)
                    acc[p] = fmaf(wq[ic * 11 + k], buf[p + k + 3], acc[p]);
        }
        // 16B/lane at 64B stride: plain stores so L2 merges lines
        float* po = out + n * 1048576 + (128 + oc) * 4096 + row * 64 + x0;
#pragma unroll
        for (int t = 0; t < 2; t++) {
            f4 v; v.x = acc[t * 4]; v.y = acc[t * 4 + 1]; v.z = acc[t * 4 + 2]; v.w = acc[t * 4 + 3];
            *reinterpret_cast<f4*>(po + t * 4) = v;
        }
        return;
    }

    {
        // ---------------- conv_hw: 3x3, streamed input rows ----------------------
        int b = blk - 16384;                         // 0..4095 : 64 n * 16 g * 4 strips
        int n = b >> 6, g = (b >> 2) & 15, strip = b & 3;
        int oc = g * 4 + wave;
        float wq[36];
        quant_bcast<36>(w_hw + oc * 36, s_hw[0], wq);
        float bz = b_hw[oc];
        int yp = strip * 16 + (lane >> 3) * 2;       // 2 rows per thread
        int x0 = (lane & 7) << 3;                    // lanes 0..7 span a full row

        float acc[2][8];
#pragma unroll
        for (int r = 0; r < 2; r++)
#pragma unroll
            for (int p = 0; p < 8; p++) acc[r][p] = bz;

        const float* xin = x + n * 1048576 + (192 + g * 4) * 4096;
#pragma unroll
        for (int ic = 0; ic < 4; ic++) {
            const float* pl = xin + ic * 4096;
#pragma unroll
            for (int iy = 0; iy < 4; iy++) {         // stream rows yp-1 .. yp+2
                int y  = yp - 1 + iy;
                int yc = min(max(y, 0), 63);
                bool yok = (y == yc);
                float rowb[16];                      // px x0-4 .. x0+11
#pragma unroll
                for (int t = 0; t < 4; t++) {
                    int xb = x0 - 4 + t * 4;
                    int xc = min(max(xb, 0), 60);
                    f4 v = ld4(pl + yc * 64 + xc);
                    if (!yok || xb != xc) { v.x = 0.f; v.y = 0.f; v.z = 0.f; v.w = 0.f; }
                    rowb[t * 4 + 0] = v.x; rowb[t * 4 + 1] = v.y;
                    rowb[t * 4 + 2] = v.z; rowb[t * 4 + 3] = v.w;
                }
#pragma unroll
                for (int r = 0; r < 2; r++) {
                    int ky = iy - r;                 // compile-time after unroll
                    if (ky >= 0 && ky < 3) {
#pragma unroll
                        for (int p = 0; p < 8; p++)
#pragma unroll
                            for (int kx = 0; kx < 3; kx++)
                                acc[r][p] = fmaf(wq[(ic * 3 + ky) * 3 + kx],
                                                 rowb[p + kx + 3], acc[r][p]);
                    }
                }
            }
        }
        // 16B/lane at 32B stride: plain stores so L2 merges lines
        float* po = out + n * 1048576 + (192 + oc) * 4096 + yp * 64 + x0;
#pragma unroll
        for (int r = 0; r < 2; r++)
#pragma unroll
            for (int t = 0; t < 2; t++) {
                f4 v;
                v.x = acc[r][t * 4]; v.y = acc[r][t * 4 + 1];
                v.z = acc[r][t * 4 + 2]; v.w = acc[r][t * 4 + 3];
                *reinterpret_cast<f4*>(po + r * 64 + t * 4) = v;
            }
    }
}

extern "C" void kernel_launch(void* const* d_in, const int* in_sizes, int n_in,
                              void* d_out, int out_size, void* d_ws, size_t ws_size,
                              hipStream_t stream) {
    // setup_inputs order: x, w_hw, b_hw, s_hw, w_w, b_w, s_w, w_h, b_h, s_h
    const float* x    = (const float*)d_in[0];
    const float* w_hw = (const float*)d_in[1];
    const float* b_hw = (const float*)d_in[2];
    const float* s_hw = (const float*)d_in[3];
    const float* w_w  = (const float*)d_in[4];
    const float* b_w  = (const float*)d_in[5];
    const float* s_w  = (const float*)d_in[6];
    const float* w_h  = (const float*)d_in[7];
    const float* b_h  = (const float*)d_in[8];
    const float* s_h  = (const float*)d_in[9];
    float* out = (float*)d_out;

    fused_k<<<20480, 256, 0, stream>>>(x, w_h, b_h, s_h, w_w, b_w, s_w,
                                       w_hw, b_hw, s_hw, out);
}